// Round 1
// baseline (593.609 us; speedup 1.0000x reference)
//
#include <hip/hip_runtime.h>

#define NN 100000
#define NE 1600000
#define DD 128

// ---------------- CSR build ----------------

__global__ __launch_bounds__(256) void k_count(const int* __restrict__ dst, int* __restrict__ counts) {
    int i = blockIdx.x * 256 + threadIdx.x;
    if (i < NE) atomicAdd(&counts[dst[i]], 1);
}

__global__ __launch_bounds__(256) void k_dis(const int* __restrict__ counts, float* __restrict__ dis) {
    int i = blockIdx.x * 256 + threadIdx.x;
    if (i < NN) dis[i] = rsqrtf((float)counts[i] + 1.0f);   // +1 self-loop; deg >= 1 always
}

__global__ __launch_bounds__(256) void k_scan1(const int* __restrict__ counts, int* __restrict__ offs,
                                               int* __restrict__ bsums) {
    __shared__ int sd[256];
    int t = threadIdx.x;
    int base = blockIdx.x * 1024 + t * 4;
    int v0 = (base + 0 < NN) ? counts[base + 0] : 0;
    int v1 = (base + 1 < NN) ? counts[base + 1] : 0;
    int v2 = (base + 2 < NN) ? counts[base + 2] : 0;
    int v3 = (base + 3 < NN) ? counts[base + 3] : 0;
    int s = v0 + v1 + v2 + v3;
    sd[t] = s;
    __syncthreads();
    for (int off = 1; off < 256; off <<= 1) {
        int add = (t >= off) ? sd[t - off] : 0;
        __syncthreads();
        sd[t] += add;
        __syncthreads();
    }
    int run = sd[t] - s;  // exclusive prefix within block
    if (base + 0 < NN) offs[base + 0] = run; run += v0;
    if (base + 1 < NN) offs[base + 1] = run; run += v1;
    if (base + 2 < NN) offs[base + 2] = run; run += v2;
    if (base + 3 < NN) offs[base + 3] = run;
    if (t == 255) bsums[blockIdx.x] = sd[255];
}

__global__ __launch_bounds__(256) void k_scan2(const int* __restrict__ bsums, int* __restrict__ bpre, int nb) {
    __shared__ int sd[256];
    int t = threadIdx.x;
    int v = (t < nb) ? bsums[t] : 0;
    sd[t] = v;
    __syncthreads();
    for (int off = 1; off < 256; off <<= 1) {
        int add = (t >= off) ? sd[t - off] : 0;
        __syncthreads();
        sd[t] += add;
        __syncthreads();
    }
    bpre[t] = sd[t] - v;
}

__global__ __launch_bounds__(256) void k_scan3(int* __restrict__ offs, const int* __restrict__ bpre) {
    int i = blockIdx.x * 256 + threadIdx.x;
    if (i < NN) offs[i] += bpre[i >> 10];
    if (i == 0) offs[NN] = NE;
}

__global__ __launch_bounds__(256) void k_fill(const int* __restrict__ src, const int* __restrict__ dst,
                                              const int* __restrict__ offs, int* __restrict__ cursor,
                                              int* __restrict__ csr) {
    int i = blockIdx.x * 256 + threadIdx.x;
    if (i < NE) {
        int d = dst[i];
        int p = offs[d] + atomicAdd(&cursor[d], 1);
        csr[p] = src[i];
    }
}

// ---------------- GEMM: C[N,128] = A[N,128] @ W[128,128] ----------------
// W in LDS (64KB) with bit6->bit2 XOR swizzle (2-way banked reads = free).
// Block: 256 threads, 64 rows; each thread 4 rows x 8 cols register tile.

__global__ __launch_bounds__(256) void k_gemm(const float* __restrict__ A, const float* __restrict__ W,
                                              float* __restrict__ C) {
    __shared__ float WL[DD * DD];
    int tid = threadIdx.x;
    #pragma unroll
    for (int i = 0; i < 16; i++) {
        int idx = tid * 4 + i * 1024;
        int sw = idx ^ (((idx >> 6) & 1) << 2);
        *(float4*)&WL[sw] = *(const float4*)&W[idx];
    }
    __syncthreads();

    int r0 = blockIdx.x * 64 + (tid >> 4) * 4;
    int c0 = (tid & 15) * 8;
    int cs0 = c0 ^ (((c0 >> 6) & 1) << 2);
    int cs1 = (c0 + 4) ^ ((((c0 + 4) >> 6) & 1) << 2);

    float acc[4][8];
    #pragma unroll
    for (int i = 0; i < 4; i++)
        #pragma unroll
        for (int j = 0; j < 8; j++) acc[i][j] = 0.f;

    int rr[4];
    #pragma unroll
    for (int i = 0; i < 4; i++) { int r = r0 + i; rr[i] = (r < NN) ? r : (NN - 1); }

    for (int k = 0; k < DD; k += 4) {
        float4 xa[4];
        #pragma unroll
        for (int i = 0; i < 4; i++) xa[i] = *(const float4*)&A[rr[i] * DD + k];
        #pragma unroll
        for (int kk = 0; kk < 4; kk++) {
            float4 wa = *(const float4*)&WL[(k + kk) * DD + cs0];
            float4 wb = *(const float4*)&WL[(k + kk) * DD + cs1];
            #pragma unroll
            for (int i = 0; i < 4; i++) {
                float xv = (kk == 0) ? xa[i].x : (kk == 1) ? xa[i].y : (kk == 2) ? xa[i].z : xa[i].w;
                acc[i][0] += xv * wa.x; acc[i][1] += xv * wa.y;
                acc[i][2] += xv * wa.z; acc[i][3] += xv * wa.w;
                acc[i][4] += xv * wb.x; acc[i][5] += xv * wb.y;
                acc[i][6] += xv * wb.z; acc[i][7] += xv * wb.w;
            }
        }
    }
    #pragma unroll
    for (int i = 0; i < 4; i++) {
        int r = r0 + i;
        if (r < NN) {
            float4 o0 = {acc[i][0], acc[i][1], acc[i][2], acc[i][3]};
            float4 o1 = {acc[i][4], acc[i][5], acc[i][6], acc[i][7]};
            *(float4*)&C[r * DD + c0]     = o0;
            *(float4*)&C[r * DD + c0 + 4] = o1;
        }
    }
}

// ---------------- Aggregation: out[n] = dis[n]*(sum_{s->n} dis[s] h[s]) + dis[n]^2 h[n] + b ----------------
// One wave per node, float2 per lane (512B coalesced row per edge).

__global__ __launch_bounds__(256) void k_agg(const float* __restrict__ h, const float* __restrict__ dis,
                                             const int* __restrict__ offs, const int* __restrict__ csr,
                                             const float* __restrict__ bias, float* __restrict__ outg,
                                             int relu) {
    int lane = threadIdx.x & 63;
    int node = blockIdx.x * 4 + (threadIdx.x >> 6);
    const float2* h2 = (const float2*)h;
    int beg = offs[node];
    int end = offs[node + 1];
    float ax = 0.f, ay = 0.f;
    int i = beg;
    for (; i + 4 <= end; i += 4) {
        int s0 = csr[i], s1 = csr[i + 1], s2 = csr[i + 2], s3 = csr[i + 3];
        float e0 = dis[s0], e1 = dis[s1], e2 = dis[s2], e3 = dis[s3];
        float2 v0 = h2[s0 * 64 + lane];
        float2 v1 = h2[s1 * 64 + lane];
        float2 v2 = h2[s2 * 64 + lane];
        float2 v3 = h2[s3 * 64 + lane];
        ax += v0.x * e0 + v1.x * e1 + v2.x * e2 + v3.x * e3;
        ay += v0.y * e0 + v1.y * e1 + v2.y * e2 + v3.y * e3;
    }
    for (; i < end; i++) {
        int s = csr[i];
        float e = dis[s];
        float2 v = h2[s * 64 + lane];
        ax += v.x * e; ay += v.y * e;
    }
    float dn = dis[node];
    float2 hv = h2[node * 64 + lane];
    float2 bv = ((const float2*)bias)[lane];
    float ox = dn * ax + dn * dn * hv.x + bv.x;
    float oy = dn * ay + dn * dn * hv.y + bv.y;
    if (relu) { ox = fmaxf(ox, 0.f); oy = fmaxf(oy, 0.f); }
    float2 o = {ox, oy};
    *(float2*)&outg[node * DD + lane * 2] = o;
}

// ---------------- Mean over nodes ----------------

__global__ __launch_bounds__(256) void k_mean(const float* __restrict__ g, float* __restrict__ out) {
    __shared__ float red[4][DD];
    int lane = threadIdx.x & 63;
    int half = threadIdx.x >> 6;
    const float2* g2 = (const float2*)g;
    int r0 = blockIdx.x * 512;
    int rend = (r0 + 512 < NN) ? (r0 + 512) : NN;
    float ax = 0.f, ay = 0.f;
    for (int r = r0 + half; r < rend; r += 4) {
        float2 v = g2[r * 64 + lane];
        ax += v.x; ay += v.y;
    }
    red[half][lane * 2]     = ax;
    red[half][lane * 2 + 1] = ay;
    __syncthreads();
    if (half == 0) {
        float sx = red[0][lane * 2] + red[1][lane * 2] + red[2][lane * 2] + red[3][lane * 2];
        float sy = red[0][lane * 2 + 1] + red[1][lane * 2 + 1] + red[2][lane * 2 + 1] + red[3][lane * 2 + 1];
        atomicAdd(&out[lane * 2],     sx * (1.0f / NN));
        atomicAdd(&out[lane * 2 + 1], sy * (1.0f / NN));
    }
}

// ---------------- launch ----------------

extern "C" void kernel_launch(void* const* d_in, const int* in_sizes, int n_in,
                              void* d_out, int out_size, void* d_ws, size_t ws_size,
                              hipStream_t stream) {
    const float* x  = (const float*)d_in[0];
    const int*   ei = (const int*)d_in[1];   // [2][NE] int32 (JAX default x64-disabled)
    const float* W1 = (const float*)d_in[2];
    const float* b1 = (const float*)d_in[3];
    const float* W2 = (const float*)d_in[4];
    const float* b2 = (const float*)d_in[5];
    float* out = (float*)d_out;
    const int* esrc = ei;
    const int* edst = ei + NE;

    char* p = (char*)d_ws;
    float* dis  = (float*)p;  p += ((size_t)NN * 4 + 255) & ~(size_t)255;
    int* counts = (int*)p;    p += ((size_t)NN * 4 + 255) & ~(size_t)255;   // reused as cursor
    int* offs   = (int*)p;    p += ((size_t)(NN + 1) * 4 + 255) & ~(size_t)255;
    int* bsums  = (int*)p;    p += 1024;
    int* bpre   = (int*)p;    p += 1024;
    int* csr    = (int*)p;    p += ((size_t)NE * 4 + 255) & ~(size_t)255;
    float* h    = (float*)p;  p += (size_t)NN * DD * 4;
    float* g    = (float*)p;  p += (size_t)NN * DD * 4;

    // CSR build (reused by both layers)
    hipMemsetAsync(counts, 0, NN * 4, stream);
    k_count<<<(NE + 255) / 256, 256, 0, stream>>>(edst, counts);
    k_dis<<<(NN + 255) / 256, 256, 0, stream>>>(counts, dis);
    int nb = (NN + 1023) / 1024;  // 98
    k_scan1<<<nb, 256, 0, stream>>>(counts, offs, bsums);
    k_scan2<<<1, 256, 0, stream>>>(bsums, bpre, nb);
    k_scan3<<<(NN + 255) / 256, 256, 0, stream>>>(offs, bpre);
    hipMemsetAsync(counts, 0, NN * 4, stream);
    k_fill<<<(NE + 255) / 256, 256, 0, stream>>>(esrc, edst, offs, counts, csr);

    // Layer 1
    k_gemm<<<(NN + 63) / 64, 256, 0, stream>>>(x, W1, h);
    k_agg<<<NN / 4, 256, 0, stream>>>(h, dis, offs, csr, b1, g, 1);
    // Layer 2
    k_gemm<<<(NN + 63) / 64, 256, 0, stream>>>(g, W2, h);
    k_agg<<<NN / 4, 256, 0, stream>>>(h, dis, offs, csr, b2, g, 0);
    // Mean
    hipMemsetAsync(out, 0, DD * sizeof(float), stream);
    k_mean<<<(NN + 511) / 512, 256, 0, stream>>>(g, out);
}

// Round 2
// 388.535 us; speedup vs baseline: 1.5278x; 1.5278x over previous
//
#include <hip/hip_runtime.h>

#define NN 100000
#define NE 1600000
#define DD 128
#define NB 196          // ceil(NN / 512) buckets of 512 nodes
#define NPB 1024        // partial blocks for fused mean

static __device__ __forceinline__ unsigned short f2bf(float f) {
    unsigned u = __float_as_uint(f);
    return (unsigned short)((u + 0x7fffu + ((u >> 16) & 1u)) >> 16);
}

// ---------------- CSR build: bucket histogram ----------------

__global__ __launch_bounds__(256) void k_bhist(const int* __restrict__ dst, int* __restrict__ bhist) {
    __shared__ int h[NB];
    int t = threadIdx.x;
    if (t < NB) h[t] = 0;
    __syncthreads();
    for (int i = blockIdx.x * 256 + t; i < NE; i += gridDim.x * 256)
        atomicAdd(&h[dst[i] >> 9], 1);
    __syncthreads();
    if (t < NB) atomicAdd(&bhist[t], h[t]);
}

__global__ __launch_bounds__(256) void k_bscan(const int* __restrict__ bhist, int* __restrict__ bbase,
                                               int* __restrict__ bcursor, int* __restrict__ offs) {
    __shared__ int sd[256];
    int t = threadIdx.x;
    int v = (t < NB) ? bhist[t] : 0;
    sd[t] = v;
    __syncthreads();
    for (int off = 1; off < 256; off <<= 1) {
        int a = (t >= off) ? sd[t - off] : 0;
        __syncthreads();
        sd[t] += a;
        __syncthreads();
    }
    if (t < NB) { int e = sd[t] - v; bbase[t] = e; bcursor[t] = e; }
    if (t == 0) { bbase[NB] = NE; offs[NN] = NE; }
}

// partition edges into buckets (append streams, LDS-staged ranks)
__global__ __launch_bounds__(256) void k_part(const int* __restrict__ src, const int* __restrict__ dst,
                                              int* __restrict__ bcursor, uint2* __restrict__ part) {
    __shared__ int hist[NB], rank[NB], bbl[NB];
    int t = threadIdx.x;
    if (t < NB) hist[t] = 0;
    __syncthreads();
    int base = blockIdx.x * 4096;
    int s[16], d[16];
    #pragma unroll
    for (int j = 0; j < 16; j++) {
        int i = base + j * 256 + t;
        if (i < NE) { s[j] = src[i]; d[j] = dst[i]; atomicAdd(&hist[d[j] >> 9], 1); }
        else d[j] = -1;
    }
    __syncthreads();
    if (t < NB) { bbl[t] = atomicAdd(&bcursor[t], hist[t]); rank[t] = 0; }
    __syncthreads();
    #pragma unroll
    for (int j = 0; j < 16; j++) {
        if (d[j] >= 0) {
            int b = d[j] >> 9;
            int r = atomicAdd(&rank[b], 1);
            part[bbl[b] + r] = make_uint2((unsigned)s[j], (unsigned)d[j]);
        }
    }
}

// per-bucket: per-node counts -> offs, dis; then scatter src into contiguous CSR region
__global__ __launch_bounds__(256) void k_csr(const uint2* __restrict__ part, const int* __restrict__ bbase,
                                             int* __restrict__ offs, float* __restrict__ dis,
                                             int* __restrict__ csr) {
    __shared__ int cnt[512], offl[512], s2[256];
    int t = threadIdx.x;
    int b = blockIdx.x;
    int dlo = b << 9;
    int nn_b = NN - dlo; if (nn_b > 512) nn_b = 512;
    int e0 = bbase[b], e1 = bbase[b + 1];
    cnt[t] = 0; cnt[t + 256] = 0;
    __syncthreads();
    for (int i = e0 + t; i < e1; i += 256)
        atomicAdd(&cnt[(int)part[i].y - dlo], 1);
    __syncthreads();
    int a0 = cnt[2 * t], a1 = cnt[2 * t + 1];
    s2[t] = a0 + a1;
    __syncthreads();
    for (int off = 1; off < 256; off <<= 1) {
        int a = (t >= off) ? s2[t - off] : 0;
        __syncthreads();
        s2[t] += a;
        __syncthreads();
    }
    int ex = s2[t] - (a0 + a1);
    offl[2 * t] = ex; offl[2 * t + 1] = ex + a0;
    __syncthreads();
    #pragma unroll
    for (int q = 0; q < 2; q++) {
        int i = t + q * 256;
        if (i < nn_b) {
            offs[dlo + i] = e0 + offl[i];
            dis[dlo + i] = rsqrtf((float)cnt[i] + 1.0f);
        }
    }
    __syncthreads();
    cnt[t] = 0; cnt[t + 256] = 0;
    __syncthreads();
    for (int i = e0 + t; i < e1; i += 256) {
        uint2 e = part[i];
        int li = (int)e.y - dlo;
        int p = e0 + offl[li] + atomicAdd(&cnt[li], 1);
        csr[p] = (int)e.x;
    }
}

// ---------------- GEMM: hs[r,:] = bf16( dis[r] * (A[r,:] @ W) ) ----------------

template<bool ABF>
__global__ __launch_bounds__(256) void k_gemm(const void* __restrict__ Ap, const float* __restrict__ W,
                                              const float* __restrict__ dis, unsigned short* __restrict__ hs) {
    __shared__ float WL[DD * DD];
    int tid = threadIdx.x;
    #pragma unroll
    for (int i = 0; i < 16; i++) {
        int idx = tid * 4 + i * 1024;
        int sw = idx ^ (((idx >> 6) & 1) << 2);
        *(float4*)&WL[sw] = *(const float4*)&W[idx];
    }
    __syncthreads();

    int r0 = blockIdx.x * 64 + (tid >> 4) * 4;
    int c0 = (tid & 15) * 8;
    int cs0 = c0 ^ (((c0 >> 6) & 1) << 2);
    int cs1 = (c0 + 4) ^ ((((c0 + 4) >> 6) & 1) << 2);

    float acc[4][8];
    #pragma unroll
    for (int i = 0; i < 4; i++)
        #pragma unroll
        for (int j = 0; j < 8; j++) acc[i][j] = 0.f;

    int rr[4];
    #pragma unroll
    for (int i = 0; i < 4; i++) { int r = r0 + i; rr[i] = (r < NN) ? r : (NN - 1); }

    for (int k = 0; k < DD; k += 4) {
        float4 xa[4];
        #pragma unroll
        for (int i = 0; i < 4; i++) {
            if constexpr (ABF) {
                uint2 u = ((const uint2*)Ap)[rr[i] * 32 + (k >> 2)];
                xa[i].x = __uint_as_float(u.x << 16);
                xa[i].y = __uint_as_float(u.x & 0xffff0000u);
                xa[i].z = __uint_as_float(u.y << 16);
                xa[i].w = __uint_as_float(u.y & 0xffff0000u);
            } else {
                xa[i] = ((const float4*)Ap)[rr[i] * 32 + (k >> 2)];
            }
        }
        #pragma unroll
        for (int kk = 0; kk < 4; kk++) {
            float4 wa = *(const float4*)&WL[(k + kk) * DD + cs0];
            float4 wb = *(const float4*)&WL[(k + kk) * DD + cs1];
            #pragma unroll
            for (int i = 0; i < 4; i++) {
                float xv = (kk == 0) ? xa[i].x : (kk == 1) ? xa[i].y : (kk == 2) ? xa[i].z : xa[i].w;
                acc[i][0] += xv * wa.x; acc[i][1] += xv * wa.y;
                acc[i][2] += xv * wa.z; acc[i][3] += xv * wa.w;
                acc[i][4] += xv * wb.x; acc[i][5] += xv * wb.y;
                acc[i][6] += xv * wb.z; acc[i][7] += xv * wb.w;
            }
        }
    }
    #pragma unroll
    for (int i = 0; i < 4; i++) {
        int r = r0 + i;
        if (r < NN) {
            float dn = dis[r];
            unsigned o0 = f2bf(acc[i][0] * dn) | ((unsigned)f2bf(acc[i][1] * dn) << 16);
            unsigned o1 = f2bf(acc[i][2] * dn) | ((unsigned)f2bf(acc[i][3] * dn) << 16);
            unsigned o2 = f2bf(acc[i][4] * dn) | ((unsigned)f2bf(acc[i][5] * dn) << 16);
            unsigned o3 = f2bf(acc[i][6] * dn) | ((unsigned)f2bf(acc[i][7] * dn) << 16);
            uint4 pk = {o0, o1, o2, o3};
            *(uint4*)&hs[r * DD + c0] = pk;
        }
    }
}

// ---------------- Aggregation layer 1: g[n] = bf16(relu(dis[n]*(sum hs[s] + hs[n]) + b)) ----------------

__global__ __launch_bounds__(256) void k_agg1(const unsigned* __restrict__ hs, const float* __restrict__ dis,
                                              const int* __restrict__ offs, const int* __restrict__ csr,
                                              const float* __restrict__ bias, unsigned* __restrict__ g) {
    int lane = threadIdx.x & 63;
    int node = blockIdx.x * 4 + (threadIdx.x >> 6);
    int beg = offs[node], end = offs[node + 1];
    float ax = 0.f, ay = 0.f;
    int i = beg;
    for (; i + 4 <= end; i += 4) {
        int s0 = csr[i], s1 = csr[i + 1], s2 = csr[i + 2], s3 = csr[i + 3];
        unsigned v0 = hs[s0 * 64 + lane];
        unsigned v1 = hs[s1 * 64 + lane];
        unsigned v2 = hs[s2 * 64 + lane];
        unsigned v3 = hs[s3 * 64 + lane];
        ax += __uint_as_float(v0 << 16); ay += __uint_as_float(v0 & 0xffff0000u);
        ax += __uint_as_float(v1 << 16); ay += __uint_as_float(v1 & 0xffff0000u);
        ax += __uint_as_float(v2 << 16); ay += __uint_as_float(v2 & 0xffff0000u);
        ax += __uint_as_float(v3 << 16); ay += __uint_as_float(v3 & 0xffff0000u);
    }
    for (; i < end; i++) {
        unsigned v = hs[csr[i] * 64 + lane];
        ax += __uint_as_float(v << 16); ay += __uint_as_float(v & 0xffff0000u);
    }
    unsigned sv = hs[node * 64 + lane];
    float dn = dis[node];
    float2 bv = ((const float2*)bias)[lane];
    float ox = dn * (ax + __uint_as_float(sv << 16)) + bv.x;
    float oy = dn * (ay + __uint_as_float(sv & 0xffff0000u)) + bv.y;
    ox = fmaxf(ox, 0.f); oy = fmaxf(oy, 0.f);
    g[node * 64 + lane] = (unsigned)f2bf(ox) | ((unsigned)f2bf(oy) << 16);
}

// ---------------- Aggregation layer 2 fused with mean (partials per block) ----------------

__global__ __launch_bounds__(256) void k_agg2(const unsigned* __restrict__ hs, const float* __restrict__ dis,
                                              const int* __restrict__ offs, const int* __restrict__ csr,
                                              float* __restrict__ partials) {
    __shared__ float red[4][DD];
    int lane = threadIdx.x & 63;
    int w = threadIdx.x >> 6;
    float mx = 0.f, my = 0.f;
    int nw = gridDim.x * 4;
    for (int node = blockIdx.x * 4 + w; node < NN; node += nw) {
        int beg = offs[node], end = offs[node + 1];
        float ax = 0.f, ay = 0.f;
        int i = beg;
        for (; i + 4 <= end; i += 4) {
            int s0 = csr[i], s1 = csr[i + 1], s2 = csr[i + 2], s3 = csr[i + 3];
            unsigned v0 = hs[s0 * 64 + lane];
            unsigned v1 = hs[s1 * 64 + lane];
            unsigned v2 = hs[s2 * 64 + lane];
            unsigned v3 = hs[s3 * 64 + lane];
            ax += __uint_as_float(v0 << 16); ay += __uint_as_float(v0 & 0xffff0000u);
            ax += __uint_as_float(v1 << 16); ay += __uint_as_float(v1 & 0xffff0000u);
            ax += __uint_as_float(v2 << 16); ay += __uint_as_float(v2 & 0xffff0000u);
            ax += __uint_as_float(v3 << 16); ay += __uint_as_float(v3 & 0xffff0000u);
        }
        for (; i < end; i++) {
            unsigned v = hs[csr[i] * 64 + lane];
            ax += __uint_as_float(v << 16); ay += __uint_as_float(v & 0xffff0000u);
        }
        unsigned sv = hs[node * 64 + lane];
        float dn = dis[node];
        mx += dn * (ax + __uint_as_float(sv << 16));
        my += dn * (ay + __uint_as_float(sv & 0xffff0000u));
    }
    red[w][2 * lane] = mx; red[w][2 * lane + 1] = my;
    __syncthreads();
    if (w == 0) {
        float sx = red[0][2 * lane] + red[1][2 * lane] + red[2][2 * lane] + red[3][2 * lane];
        float sy = red[0][2 * lane + 1] + red[1][2 * lane + 1] + red[2][2 * lane + 1] + red[3][2 * lane + 1];
        partials[blockIdx.x * DD + 2 * lane] = sx;
        partials[blockIdx.x * DD + 2 * lane + 1] = sy;
    }
}

__global__ __launch_bounds__(128) void k_final(const float* __restrict__ partials, const float* __restrict__ b2,
                                               float* __restrict__ out) {
    int t = threadIdx.x;
    float s = 0.f;
    for (int p = 0; p < NPB; p++) s += partials[p * DD + t];
    out[t] = s * (1.0f / NN) + b2[t];
}

// ---------------- launch ----------------

extern "C" void kernel_launch(void* const* d_in, const int* in_sizes, int n_in,
                              void* d_out, int out_size, void* d_ws, size_t ws_size,
                              hipStream_t stream) {
    const float* x  = (const float*)d_in[0];
    const int*   ei = (const int*)d_in[1];
    const float* W1 = (const float*)d_in[2];
    const float* b1 = (const float*)d_in[3];
    const float* W2 = (const float*)d_in[4];
    const float* b2 = (const float*)d_in[5];
    float* out = (float*)d_out;
    const int* esrc = ei;
    const int* edst = ei + NE;

    char* p = (char*)d_ws;
    uint2* part    = (uint2*)p;          p += (size_t)NE * 8;
    int* csr       = (int*)p;            p += (size_t)NE * 4;
    int* offs      = (int*)p;            p += (((size_t)(NN + 1) * 4) + 255) & ~(size_t)255;
    float* dis     = (float*)p;          p += (((size_t)NN * 4) + 255) & ~(size_t)255;
    int* bhist     = (int*)p;            p += 1024;
    int* bbase     = (int*)p;            p += 1024;
    int* bcursor   = (int*)p;            p += 1024;
    unsigned short* hs = (unsigned short*)p;  p += (size_t)NN * DD * 2;
    unsigned* g    = (unsigned*)p;       p += (size_t)NN * DD * 2;
    float* partials = (float*)p;         p += (size_t)NPB * DD * 4;

    // CSR build
    hipMemsetAsync(bhist, 0, NB * 4, stream);
    k_bhist<<<256, 256, 0, stream>>>(edst, bhist);
    k_bscan<<<1, 256, 0, stream>>>(bhist, bbase, bcursor, offs);
    k_part<<<(NE + 4095) / 4096, 256, 0, stream>>>(esrc, edst, bcursor, part);
    k_csr<<<NB, 256, 0, stream>>>(part, bbase, offs, dis, csr);

    // Layer 1
    k_gemm<false><<<(NN + 63) / 64, 256, 0, stream>>>(x, W1, dis, hs);
    k_agg1<<<NN / 4, 256, 0, stream>>>((const unsigned*)hs, dis, offs, csr, b1, g);
    // Layer 2
    k_gemm<true><<<(NN + 63) / 64, 256, 0, stream>>>(g, W2, dis, hs);
    k_agg2<<<NPB, 256, 0, stream>>>((const unsigned*)hs, dis, offs, csr, partials);
    k_final<<<1, 128, 0, stream>>>(partials, b2, out);
}

// Round 3
// 291.527 us; speedup vs baseline: 2.0362x; 1.3328x over previous
//
#include <hip/hip_runtime.h>

#define NN 100000
#define NE 1600000
#define DD 128
#define NB 196          // ceil(NN/512) buckets of 512 nodes
#define NAB 3125        // k_agg2 blocks: 3125*4 waves*8 nodes = 100000 exactly

typedef float f32x2 __attribute__((ext_vector_type(2)));
typedef float f32x4 __attribute__((ext_vector_type(4)));
typedef short s16x8 __attribute__((ext_vector_type(8)));

static __device__ __forceinline__ unsigned short f2bf(float f) {
    unsigned u = __float_as_uint(f);
    return (unsigned short)((u + 0x7fffu + ((u >> 16) & 1u)) >> 16);
}

// ---------------- CSR build ----------------

__global__ __launch_bounds__(256) void k_bhist(const int* __restrict__ dst, int* __restrict__ bhist) {
    __shared__ int h[NB];
    int t = threadIdx.x;
    if (t < NB) h[t] = 0;
    __syncthreads();
    for (int i = blockIdx.x * 256 + t; i < NE; i += gridDim.x * 256)
        atomicAdd(&h[dst[i] >> 9], 1);
    __syncthreads();
    if (t < NB) atomicAdd(&bhist[t], h[t]);
}

__global__ __launch_bounds__(256) void k_bscan(const int* __restrict__ bhist, int* __restrict__ bbase,
                                               int* __restrict__ bcursor, int* __restrict__ offs) {
    __shared__ int sd[256];
    int t = threadIdx.x;
    int v = (t < NB) ? bhist[t] : 0;
    sd[t] = v;
    __syncthreads();
    for (int off = 1; off < 256; off <<= 1) {
        int a = (t >= off) ? sd[t - off] : 0;
        __syncthreads();
        sd[t] += a;
        __syncthreads();
    }
    if (t < NB) { int e = sd[t] - v; bbase[t] = e; bcursor[t] = e; }
    if (t == 0) { bbase[NB] = NE; offs[NN] = NE; }
}

// partition edges into buckets; record packed as (local_dst<<17)|src  (src<2^17, ldst<2^9)
__global__ __launch_bounds__(256) void k_part(const int* __restrict__ src, const int* __restrict__ dst,
                                              int* __restrict__ bcursor, unsigned* __restrict__ part) {
    __shared__ int hist[NB], rank[NB], bbl[NB];
    int t = threadIdx.x;
    if (t < NB) hist[t] = 0;
    __syncthreads();
    int base = blockIdx.x * 4096;
    int s[16], d[16];
    #pragma unroll
    for (int j = 0; j < 16; j++) {
        int i = base + j * 256 + t;
        if (i < NE) { s[j] = src[i]; d[j] = dst[i]; atomicAdd(&hist[d[j] >> 9], 1); }
        else d[j] = -1;
    }
    __syncthreads();
    if (t < NB) { bbl[t] = atomicAdd(&bcursor[t], hist[t]); rank[t] = 0; }
    __syncthreads();
    #pragma unroll
    for (int j = 0; j < 16; j++) {
        if (d[j] >= 0) {
            int b = d[j] >> 9;
            int r = atomicAdd(&rank[b], 1);
            part[bbl[b] + r] = (unsigned)s[j] | ((unsigned)(d[j] & 511) << 17);
        }
    }
}

__global__ __launch_bounds__(256) void k_csr(const unsigned* __restrict__ part, const int* __restrict__ bbase,
                                             int* __restrict__ offs, float* __restrict__ dis,
                                             int* __restrict__ csr) {
    __shared__ int cnt[512], offl[512], s2[256];
    int t = threadIdx.x;
    int b = blockIdx.x;
    int dlo = b << 9;
    int nn_b = NN - dlo; if (nn_b > 512) nn_b = 512;
    int e0 = bbase[b], e1 = bbase[b + 1];
    cnt[t] = 0; cnt[t + 256] = 0;
    __syncthreads();
    for (int i = e0 + t; i < e1; i += 256)
        atomicAdd(&cnt[part[i] >> 17], 1);
    __syncthreads();
    int a0 = cnt[2 * t], a1 = cnt[2 * t + 1];
    s2[t] = a0 + a1;
    __syncthreads();
    for (int off = 1; off < 256; off <<= 1) {
        int a = (t >= off) ? s2[t - off] : 0;
        __syncthreads();
        s2[t] += a;
        __syncthreads();
    }
    int ex = s2[t] - (a0 + a1);
    offl[2 * t] = ex; offl[2 * t + 1] = ex + a0;
    __syncthreads();
    #pragma unroll
    for (int q = 0; q < 2; q++) {
        int i = t + q * 256;
        if (i < nn_b) {
            offs[dlo + i] = e0 + offl[i];
            dis[dlo + i] = rsqrtf((float)cnt[i] + 1.0f);
        }
    }
    __syncthreads();
    cnt[t] = 0; cnt[t + 256] = 0;
    __syncthreads();
    for (int i = e0 + t; i < e1; i += 256) {
        unsigned e = part[i];
        int li = (int)(e >> 17);
        int p = e0 + offl[li] + atomicAdd(&cnt[li], 1);
        csr[p] = (int)(e & 0x1FFFFu);
    }
}

// ---------------- MFMA GEMM: hs[r,:] = fp8( dis[r] * (A[r,:] @ W) ) ----------------
// Swapped-operand trick: mfma(Wfrag, Afrag) -> lane holds row (lane&15),
// cols nt*16 + (lane>>4)*4 + r  => pack 4 fp8 into one u32 store. No LDS epilogue.

template<bool ABF>
__global__ __launch_bounds__(256) void k_gemm(const void* __restrict__ Ap, const float* __restrict__ W,
                                              const float* __restrict__ dis, unsigned* __restrict__ hs) {
    __shared__ unsigned WF[8192];   // 8nt x 4kk x 64lane x 4 u32 (bf16 pairs), 32KB
    int tid = threadIdx.x;
    #pragma unroll
    for (int i = 0; i < 32; i++) {
        int e = i * 256 + tid;
        int jw = e & 3, lane = (e >> 2) & 63, kk = (e >> 8) & 3, nt = e >> 10;
        int r0 = kk * 32 + ((lane >> 4) << 3) + (jw << 1);
        int c = (nt << 4) + (lane & 15);
        unsigned lo = f2bf(W[r0 * DD + c]);
        unsigned hi = f2bf(W[(r0 + 1) * DD + c]);
        WF[e] = lo | (hi << 16);
    }
    __syncthreads();

    int lane = tid & 63;
    int w = tid >> 6;
    int rowBase = blockIdx.x * 128 + w * 32;
    int lg = lane >> 4;
    int ll = lane & 15;

    f32x4 acc[2][8];
    #pragma unroll
    for (int m = 0; m < 2; m++)
        #pragma unroll
        for (int n = 0; n < 8; n++) acc[m][n] = (f32x4){0.f, 0.f, 0.f, 0.f};

    const s16x8* wfrag = (const s16x8*)WF;

    for (int kk = 0; kk < 4; kk++) {
        s16x8 af[2];
        #pragma unroll
        for (int mt = 0; mt < 2; mt++) {
            int r = rowBase + mt * 16 + ll;
            if (r >= NN) r = NN - 1;
            if constexpr (ABF) {
                af[mt] = *(const s16x8*)((const unsigned short*)Ap + (size_t)r * DD + kk * 32 + lg * 8);
            } else {
                const float* xp = (const float*)Ap + (size_t)r * DD + kk * 32 + lg * 8;
                f32x4 a0 = *(const f32x4*)xp;
                f32x4 a1 = *(const f32x4*)(xp + 4);
                s16x8 t;
                t[0] = (short)f2bf(a0[0]); t[1] = (short)f2bf(a0[1]);
                t[2] = (short)f2bf(a0[2]); t[3] = (short)f2bf(a0[3]);
                t[4] = (short)f2bf(a1[0]); t[5] = (short)f2bf(a1[1]);
                t[6] = (short)f2bf(a1[2]); t[7] = (short)f2bf(a1[3]);
                af[mt] = t;
            }
        }
        #pragma unroll
        for (int nt = 0; nt < 8; nt++) {
            s16x8 bf = wfrag[(nt * 4 + kk) * 64 + lane];
            acc[0][nt] = __builtin_amdgcn_mfma_f32_16x16x32_bf16(bf, af[0], acc[0][nt], 0, 0, 0);
            acc[1][nt] = __builtin_amdgcn_mfma_f32_16x16x32_bf16(bf, af[1], acc[1][nt], 0, 0, 0);
        }
    }

    #pragma unroll
    for (int mt = 0; mt < 2; mt++) {
        int grow = rowBase + mt * 16 + ll;
        if (grow < NN) {
            float dn = dis[grow];
            unsigned* orow = hs + (size_t)grow * 32;
            #pragma unroll
            for (int nt = 0; nt < 8; nt++) {
                f32x4 v = acc[mt][nt];
                int u = 0;
                u = __builtin_amdgcn_cvt_pk_fp8_f32(v[0] * dn, v[1] * dn, u, false);
                u = __builtin_amdgcn_cvt_pk_fp8_f32(v[2] * dn, v[3] * dn, u, true);
                orow[nt * 4 + lg] = (unsigned)u;
            }
        }
    }
}

// ---------------- Aggregation layer 1: g = bf16(relu(dis[n]*(sum + self) + b)) ----------------

__global__ __launch_bounds__(256) void k_agg1(const unsigned short* __restrict__ hs, const float* __restrict__ dis,
                                              const int* __restrict__ offs, const int* __restrict__ csr,
                                              const float* __restrict__ bias, unsigned* __restrict__ g) {
    int lane = threadIdx.x & 63;
    int node = blockIdx.x * 4 + (threadIdx.x >> 6);
    int beg = offs[node], end = offs[node + 1];
    float ax = 0.f, ay = 0.f;
    int i = beg;
    for (; i + 4 <= end; i += 4) {
        int s0 = csr[i], s1 = csr[i + 1], s2 = csr[i + 2], s3 = csr[i + 3];
        unsigned u0 = hs[s0 * 64 + lane];
        unsigned u1 = hs[s1 * 64 + lane];
        unsigned u2 = hs[s2 * 64 + lane];
        unsigned u3 = hs[s3 * 64 + lane];
        f32x2 v0 = __builtin_amdgcn_cvt_pk_f32_fp8(u0, false);
        f32x2 v1 = __builtin_amdgcn_cvt_pk_f32_fp8(u1, false);
        f32x2 v2 = __builtin_amdgcn_cvt_pk_f32_fp8(u2, false);
        f32x2 v3 = __builtin_amdgcn_cvt_pk_f32_fp8(u3, false);
        ax += v0[0] + v1[0] + v2[0] + v3[0];
        ay += v0[1] + v1[1] + v2[1] + v3[1];
    }
    for (; i < end; i++) {
        unsigned u = hs[csr[i] * 64 + lane];
        f32x2 v = __builtin_amdgcn_cvt_pk_f32_fp8(u, false);
        ax += v[0]; ay += v[1];
    }
    unsigned su = hs[node * 64 + lane];
    f32x2 sv = __builtin_amdgcn_cvt_pk_f32_fp8(su, false);
    float dn = dis[node];
    float2 bv = ((const float2*)bias)[lane];
    float ox = fmaxf(dn * (ax + sv[0]) + bv.x, 0.f);
    float oy = fmaxf(dn * (ay + sv[1]) + bv.y, 0.f);
    g[node * 64 + lane] = (unsigned)f2bf(ox) | ((unsigned)f2bf(oy) << 16);
}

// ---------------- Aggregation layer 2 fused with mean ----------------

__global__ __launch_bounds__(256) void k_agg2(const unsigned short* __restrict__ hs, const float* __restrict__ dis,
                                              const int* __restrict__ offs, const int* __restrict__ csr,
                                              float* __restrict__ partials) {
    __shared__ float red[4][DD];
    int lane = threadIdx.x & 63;
    int w = threadIdx.x >> 6;
    float mx = 0.f, my = 0.f;
    int nb0 = (blockIdx.x * 4 + w) * 8;
    #pragma unroll 1
    for (int q = 0; q < 8; q++) {
        int node = nb0 + q;
        if (node >= NN) break;
        int beg = offs[node], end = offs[node + 1];
        float ax = 0.f, ay = 0.f;
        int i = beg;
        for (; i + 4 <= end; i += 4) {
            int s0 = csr[i], s1 = csr[i + 1], s2 = csr[i + 2], s3 = csr[i + 3];
            unsigned u0 = hs[s0 * 64 + lane];
            unsigned u1 = hs[s1 * 64 + lane];
            unsigned u2 = hs[s2 * 64 + lane];
            unsigned u3 = hs[s3 * 64 + lane];
            f32x2 v0 = __builtin_amdgcn_cvt_pk_f32_fp8(u0, false);
            f32x2 v1 = __builtin_amdgcn_cvt_pk_f32_fp8(u1, false);
            f32x2 v2 = __builtin_amdgcn_cvt_pk_f32_fp8(u2, false);
            f32x2 v3 = __builtin_amdgcn_cvt_pk_f32_fp8(u3, false);
            ax += v0[0] + v1[0] + v2[0] + v3[0];
            ay += v0[1] + v1[1] + v2[1] + v3[1];
        }
        for (; i < end; i++) {
            unsigned u = hs[csr[i] * 64 + lane];
            f32x2 v = __builtin_amdgcn_cvt_pk_f32_fp8(u, false);
            ax += v[0]; ay += v[1];
        }
        unsigned su = hs[node * 64 + lane];
        f32x2 sv = __builtin_amdgcn_cvt_pk_f32_fp8(su, false);
        float dn = dis[node];
        mx += dn * (ax + sv[0]);
        my += dn * (ay + sv[1]);
    }
    red[w][2 * lane] = mx; red[w][2 * lane + 1] = my;
    __syncthreads();
    if (w == 0) {
        float sx = red[0][2 * lane] + red[1][2 * lane] + red[2][2 * lane] + red[3][2 * lane];
        float sy = red[0][2 * lane + 1] + red[1][2 * lane + 1] + red[2][2 * lane + 1] + red[3][2 * lane + 1];
        partials[blockIdx.x * DD + 2 * lane] = sx;
        partials[blockIdx.x * DD + 2 * lane + 1] = sy;
    }
}

__global__ __launch_bounds__(128) void k_red1(const float* __restrict__ partials, float* __restrict__ s1) {
    int t = threadIdx.x, b = blockIdx.x;
    float s = 0.f;
    for (int r = b * 25; r < b * 25 + 25; r++) s += partials[r * DD + t];
    s1[b * DD + t] = s;
}

__global__ __launch_bounds__(128) void k_red2(const float* __restrict__ s1, const float* __restrict__ b2,
                                              float* __restrict__ out) {
    int t = threadIdx.x;
    float s = 0.f;
    for (int r = 0; r < 125; r++) s += s1[r * DD + t];
    out[t] = s * (1.0f / NN) + b2[t];
}

// ---------------- launch ----------------

extern "C" void kernel_launch(void* const* d_in, const int* in_sizes, int n_in,
                              void* d_out, int out_size, void* d_ws, size_t ws_size,
                              hipStream_t stream) {
    const float* x  = (const float*)d_in[0];
    const int*   ei = (const int*)d_in[1];
    const float* W1 = (const float*)d_in[2];
    const float* b1 = (const float*)d_in[3];
    const float* W2 = (const float*)d_in[4];
    const float* b2 = (const float*)d_in[5];
    float* out = (float*)d_out;
    const int* esrc = ei;
    const int* edst = ei + NE;

    char* p = (char*)d_ws;
    unsigned* part = (unsigned*)p;       p += (size_t)NE * 4;
    int* csr       = (int*)p;            p += (size_t)NE * 4;
    int* offs      = (int*)p;            p += (((size_t)(NN + 1) * 4) + 255) & ~(size_t)255;
    float* dis     = (float*)p;          p += (((size_t)NN * 4) + 255) & ~(size_t)255;
    int* bhist     = (int*)p;            p += 1024;
    int* bbase     = (int*)p;            p += 1024;
    int* bcursor   = (int*)p;            p += 1024;
    unsigned* hs   = (unsigned*)p;       p += (size_t)NN * DD;          // fp8: 1B/elem
    unsigned* g    = (unsigned*)p;       p += (size_t)NN * DD * 2;      // bf16
    float* partials = (float*)p;         p += (size_t)NAB * DD * 4;
    float* s1      = (float*)p;          p += (size_t)125 * DD * 4;

    // CSR build
    hipMemsetAsync(bhist, 0, NB * 4, stream);
    k_bhist<<<256, 256, 0, stream>>>(edst, bhist);
    k_bscan<<<1, 256, 0, stream>>>(bhist, bbase, bcursor, offs);
    k_part<<<(NE + 4095) / 4096, 256, 0, stream>>>(esrc, edst, bcursor, part);
    k_csr<<<NB, 256, 0, stream>>>(part, bbase, offs, dis, csr);

    // Layer 1
    k_gemm<false><<<(NN + 127) / 128, 256, 0, stream>>>(x, W1, dis, hs);
    k_agg1<<<NN / 4, 256, 0, stream>>>((const unsigned short*)hs, dis, offs, csr, b1, g);
    // Layer 2
    k_gemm<true><<<(NN + 127) / 128, 256, 0, stream>>>(g, W2, dis, hs);
    k_agg2<<<NAB, 256, 0, stream>>>((const unsigned short*)hs, dis, offs, csr, partials);
    k_red1<<<125, 128, 0, stream>>>(partials, s1);
    k_red2<<<1, 128, 0, stream>>>(s1, b2, out);
}

// Round 4
// 290.568 us; speedup vs baseline: 2.0429x; 1.0033x over previous
//
#include <hip/hip_runtime.h>

#define NN 100000
#define NE 1600000
#define DD 128
#define NB 196          // ceil(NN/512) buckets of 512 nodes
#define NWB 256         // k_wsum partial blocks

typedef float f32x2 __attribute__((ext_vector_type(2)));
typedef float f32x4 __attribute__((ext_vector_type(4)));
typedef short s16x8 __attribute__((ext_vector_type(8)));

static __device__ __forceinline__ unsigned short f2bf(float f) {
    unsigned u = __float_as_uint(f);
    return (unsigned short)((u + 0x7fffu + ((u >> 16) & 1u)) >> 16);
}

// ---------------- CSR build ----------------

__global__ __launch_bounds__(256) void k_bhist(const int* __restrict__ dst, int* __restrict__ bhist) {
    __shared__ int h[NB];
    int t = threadIdx.x;
    if (t < NB) h[t] = 0;
    __syncthreads();
    for (int i = blockIdx.x * 256 + t; i < NE; i += gridDim.x * 256)
        atomicAdd(&h[dst[i] >> 9], 1);
    __syncthreads();
    if (t < NB) atomicAdd(&bhist[t], h[t]);
}

__global__ __launch_bounds__(256) void k_bscan(const int* __restrict__ bhist, int* __restrict__ bbase,
                                               int* __restrict__ bcursor, int* __restrict__ offs) {
    __shared__ int sd[256];
    int t = threadIdx.x;
    int v = (t < NB) ? bhist[t] : 0;
    sd[t] = v;
    __syncthreads();
    for (int off = 1; off < 256; off <<= 1) {
        int a = (t >= off) ? sd[t - off] : 0;
        __syncthreads();
        sd[t] += a;
        __syncthreads();
    }
    if (t < NB) { int e = sd[t] - v; bbase[t] = e; bcursor[t] = e; }
    if (t == 0) { bbase[NB] = NE; offs[NN] = NE; }
}

// partition edges into buckets; record packed as (local_dst<<17)|src
__global__ __launch_bounds__(256) void k_part(const int* __restrict__ src, const int* __restrict__ dst,
                                              int* __restrict__ bcursor, unsigned* __restrict__ part) {
    __shared__ int hist[NB], rank[NB], bbl[NB];
    int t = threadIdx.x;
    if (t < NB) hist[t] = 0;
    __syncthreads();
    int base = blockIdx.x * 4096;
    int s[16], d[16];
    #pragma unroll
    for (int j = 0; j < 16; j++) {
        int i = base + j * 256 + t;
        if (i < NE) { s[j] = src[i]; d[j] = dst[i]; atomicAdd(&hist[d[j] >> 9], 1); }
        else d[j] = -1;
    }
    __syncthreads();
    if (t < NB) { bbl[t] = atomicAdd(&bcursor[t], hist[t]); rank[t] = 0; }
    __syncthreads();
    #pragma unroll
    for (int j = 0; j < 16; j++) {
        if (d[j] >= 0) {
            int b = d[j] >> 9;
            int r = atomicAdd(&rank[b], 1);
            part[bbl[b] + r] = (unsigned)s[j] | ((unsigned)(d[j] & 511) << 17);
        }
    }
}

// per-bucket CSR + dis; also accumulates coef[src] += dis[dst] (for layer-2 collapse)
__global__ __launch_bounds__(256) void k_csr(const unsigned* __restrict__ part, const int* __restrict__ bbase,
                                             int* __restrict__ offs, float* __restrict__ dis,
                                             int* __restrict__ csr, float* __restrict__ coef) {
    __shared__ int cnt[512], offl[512], s2[256];
    __shared__ float disl[512];
    int t = threadIdx.x;
    int b = blockIdx.x;
    int dlo = b << 9;
    int nn_b = NN - dlo; if (nn_b > 512) nn_b = 512;
    int e0 = bbase[b], e1 = bbase[b + 1];
    cnt[t] = 0; cnt[t + 256] = 0;
    __syncthreads();
    for (int i = e0 + t; i < e1; i += 256)
        atomicAdd(&cnt[part[i] >> 17], 1);
    __syncthreads();
    int a0 = cnt[2 * t], a1 = cnt[2 * t + 1];
    s2[t] = a0 + a1;
    __syncthreads();
    for (int off = 1; off < 256; off <<= 1) {
        int a = (t >= off) ? s2[t - off] : 0;
        __syncthreads();
        s2[t] += a;
        __syncthreads();
    }
    int ex = s2[t] - (a0 + a1);
    offl[2 * t] = ex; offl[2 * t + 1] = ex + a0;
    __syncthreads();
    #pragma unroll
    for (int q = 0; q < 2; q++) {
        int i = t + q * 256;
        if (i < nn_b) {
            float dv = rsqrtf((float)cnt[i] + 1.0f);
            offs[dlo + i] = e0 + offl[i];
            dis[dlo + i] = dv;
            disl[i] = dv;
        }
    }
    __syncthreads();
    cnt[t] = 0; cnt[t + 256] = 0;
    __syncthreads();
    for (int i = e0 + t; i < e1; i += 256) {
        unsigned e = part[i];
        int li = (int)(e >> 17);
        int sv = (int)(e & 0x1FFFFu);
        int p = e0 + offl[li] + atomicAdd(&cnt[li], 1);
        csr[p] = sv;
        atomicAdd(&coef[sv], disl[li]);
    }
}

// ---------------- MFMA GEMM: hs[r,:] = fp8( dis[r] * (x[r,:] @ W) ) ----------------

__global__ __launch_bounds__(256) void k_gemm(const float* __restrict__ Ap, const float* __restrict__ W,
                                              const float* __restrict__ dis, unsigned* __restrict__ hs) {
    __shared__ unsigned WF[8192];   // 8nt x 4kk x 64lane x 4 u32 (bf16 pairs), 32KB
    int tid = threadIdx.x;
    #pragma unroll
    for (int i = 0; i < 32; i++) {
        int e = i * 256 + tid;
        int jw = e & 3, lane = (e >> 2) & 63, kk = (e >> 8) & 3, nt = e >> 10;
        int r0 = kk * 32 + ((lane >> 4) << 3) + (jw << 1);
        int c = (nt << 4) + (lane & 15);
        unsigned lo = f2bf(W[r0 * DD + c]);
        unsigned hi = f2bf(W[(r0 + 1) * DD + c]);
        WF[e] = lo | (hi << 16);
    }
    __syncthreads();

    int lane = tid & 63;
    int w = tid >> 6;
    int rowBase = blockIdx.x * 128 + w * 32;
    int lg = lane >> 4;
    int ll = lane & 15;

    f32x4 acc[2][8];
    #pragma unroll
    for (int m = 0; m < 2; m++)
        #pragma unroll
        for (int n = 0; n < 8; n++) acc[m][n] = (f32x4){0.f, 0.f, 0.f, 0.f};

    const s16x8* wfrag = (const s16x8*)WF;

    for (int kk = 0; kk < 4; kk++) {
        s16x8 af[2];
        #pragma unroll
        for (int mt = 0; mt < 2; mt++) {
            int r = rowBase + mt * 16 + ll;
            if (r >= NN) r = NN - 1;
            const float* xp = Ap + (size_t)r * DD + kk * 32 + lg * 8;
            f32x4 a0 = *(const f32x4*)xp;
            f32x4 a1 = *(const f32x4*)(xp + 4);
            s16x8 tt;
            tt[0] = (short)f2bf(a0[0]); tt[1] = (short)f2bf(a0[1]);
            tt[2] = (short)f2bf(a0[2]); tt[3] = (short)f2bf(a0[3]);
            tt[4] = (short)f2bf(a1[0]); tt[5] = (short)f2bf(a1[1]);
            tt[6] = (short)f2bf(a1[2]); tt[7] = (short)f2bf(a1[3]);
            af[mt] = tt;
        }
        #pragma unroll
        for (int nt = 0; nt < 8; nt++) {
            s16x8 bf = wfrag[(nt * 4 + kk) * 64 + lane];
            acc[0][nt] = __builtin_amdgcn_mfma_f32_16x16x32_bf16(bf, af[0], acc[0][nt], 0, 0, 0);
            acc[1][nt] = __builtin_amdgcn_mfma_f32_16x16x32_bf16(bf, af[1], acc[1][nt], 0, 0, 0);
        }
    }

    #pragma unroll
    for (int mt = 0; mt < 2; mt++) {
        int grow = rowBase + mt * 16 + ll;
        if (grow < NN) {
            float dn = dis[grow];
            unsigned* orow = hs + (size_t)grow * 32;
            #pragma unroll
            for (int nt = 0; nt < 8; nt++) {
                f32x4 v = acc[mt][nt];
                int u = 0;
                u = __builtin_amdgcn_cvt_pk_fp8_f32(v[0] * dn, v[1] * dn, u, false);
                u = __builtin_amdgcn_cvt_pk_fp8_f32(v[2] * dn, v[3] * dn, u, true);
                orow[nt * 4 + lg] = (unsigned)u;
            }
        }
    }
}

// ---------------- Aggregation layer 1: g = bf16(relu(dis[n]*(sum + self) + b)) ----------------

__global__ __launch_bounds__(256) void k_agg1(const unsigned short* __restrict__ hs, const float* __restrict__ dis,
                                              const int* __restrict__ offs, const int* __restrict__ csr,
                                              const float* __restrict__ bias, unsigned* __restrict__ g) {
    int lane = threadIdx.x & 63;
    int node = blockIdx.x * 4 + (threadIdx.x >> 6);
    int beg = offs[node], end = offs[node + 1];
    float ax = 0.f, ay = 0.f;
    int i = beg;
    for (; i + 4 <= end; i += 4) {
        int s0 = csr[i], s1 = csr[i + 1], s2 = csr[i + 2], s3 = csr[i + 3];
        unsigned u0 = hs[s0 * 64 + lane];
        unsigned u1 = hs[s1 * 64 + lane];
        unsigned u2 = hs[s2 * 64 + lane];
        unsigned u3 = hs[s3 * 64 + lane];
        f32x2 v0 = __builtin_amdgcn_cvt_pk_f32_fp8(u0, false);
        f32x2 v1 = __builtin_amdgcn_cvt_pk_f32_fp8(u1, false);
        f32x2 v2 = __builtin_amdgcn_cvt_pk_f32_fp8(u2, false);
        f32x2 v3 = __builtin_amdgcn_cvt_pk_f32_fp8(u3, false);
        ax += v0[0] + v1[0] + v2[0] + v3[0];
        ay += v0[1] + v1[1] + v2[1] + v3[1];
    }
    for (; i < end; i++) {
        unsigned u = hs[csr[i] * 64 + lane];
        f32x2 v = __builtin_amdgcn_cvt_pk_f32_fp8(u, false);
        ax += v[0]; ay += v[1];
    }
    unsigned su = hs[node * 64 + lane];
    f32x2 sv = __builtin_amdgcn_cvt_pk_f32_fp8(su, false);
    float dn = dis[node];
    float2 bv = ((const float2*)bias)[lane];
    float ox = fmaxf(dn * (ax + sv[0]) + bv.x, 0.f);
    float oy = fmaxf(dn * (ay + sv[1]) + bv.y, 0.f);
    g[node * 64 + lane] = (unsigned)f2bf(ox) | ((unsigned)f2bf(oy) << 16);
}

// ---------------- Layer 2 collapsed: v = sum_s (coef[s]+dis[s])*dis[s] * g[s] ----------------

__global__ __launch_bounds__(256) void k_wsum(const unsigned* __restrict__ g, const float* __restrict__ coef,
                                              const float* __restrict__ dis, float* __restrict__ partials) {
    __shared__ float red[4][DD];
    int lane = threadIdx.x & 63;
    int w = threadIdx.x >> 6;
    int wid = blockIdx.x * 4 + w;          // 0..1023
    float ax = 0.f, ay = 0.f;
    for (int n0 = wid; n0 < NN; n0 += 4096) {
        #pragma unroll
        for (int q = 0; q < 4; q++) {
            int node = n0 + q * 1024;
            if (node < NN) {
                float dn = dis[node];
                float wt = (coef[node] + dn) * dn;
                unsigned u = g[node * 64 + lane];
                ax += wt * __uint_as_float(u << 16);
                ay += wt * __uint_as_float(u & 0xffff0000u);
            }
        }
    }
    red[w][2 * lane] = ax; red[w][2 * lane + 1] = ay;
    __syncthreads();
    if (w == 0) {
        float sx = red[0][2 * lane] + red[1][2 * lane] + red[2][2 * lane] + red[3][2 * lane];
        float sy = red[0][2 * lane + 1] + red[1][2 * lane + 1] + red[2][2 * lane + 1] + red[3][2 * lane + 1];
        partials[blockIdx.x * DD + 2 * lane] = sx;
        partials[blockIdx.x * DD + 2 * lane + 1] = sy;
    }
}

// out[t] = (1/N) * sum_k v[k] * W2[k][t] + b2[t]
__global__ __launch_bounds__(128) void k_out(const float* __restrict__ partials, const float* __restrict__ W2,
                                             const float* __restrict__ b2, float* __restrict__ out) {
    __shared__ float v[DD];
    int t = threadIdx.x;
    float s = 0.f;
    for (int p = 0; p < NWB; p++) s += partials[p * DD + t];
    v[t] = s * (1.0f / NN);
    __syncthreads();
    float o = b2[t];
    for (int k = 0; k < DD; k++) o += v[k] * W2[k * DD + t];
    out[t] = o;
}

// ---------------- launch ----------------

extern "C" void kernel_launch(void* const* d_in, const int* in_sizes, int n_in,
                              void* d_out, int out_size, void* d_ws, size_t ws_size,
                              hipStream_t stream) {
    const float* x  = (const float*)d_in[0];
    const int*   ei = (const int*)d_in[1];
    const float* W1 = (const float*)d_in[2];
    const float* b1 = (const float*)d_in[3];
    const float* W2 = (const float*)d_in[4];
    const float* b2 = (const float*)d_in[5];
    float* out = (float*)d_out;
    const int* esrc = ei;
    const int* edst = ei + NE;

    char* p = (char*)d_ws;
    unsigned* part = (unsigned*)p;       p += (size_t)NE * 4;
    int* csr       = (int*)p;            p += (size_t)NE * 4;
    int* offs      = (int*)p;            p += (((size_t)(NN + 1) * 4) + 255) & ~(size_t)255;
    float* dis     = (float*)p;          p += (((size_t)NN * 4) + 255) & ~(size_t)255;
    float* coef    = (float*)p;          p += (((size_t)NN * 4) + 255) & ~(size_t)255;
    int* bhist     = (int*)p;            p += 1024;
    int* bbase     = (int*)p;            p += 1024;
    int* bcursor   = (int*)p;            p += 1024;
    unsigned* hs   = (unsigned*)p;       p += (size_t)NN * DD;          // fp8: 1B/elem
    unsigned* g    = (unsigned*)p;       p += (size_t)NN * DD * 2;      // bf16
    float* partials = (float*)p;         p += (size_t)NWB * DD * 4;

    // CSR build (+ coef for collapsed layer 2)
    hipMemsetAsync(bhist, 0, NB * 4, stream);
    hipMemsetAsync(coef, 0, NN * 4, stream);
    k_bhist<<<256, 256, 0, stream>>>(edst, bhist);
    k_bscan<<<1, 256, 0, stream>>>(bhist, bbase, bcursor, offs);
    k_part<<<(NE + 4095) / 4096, 256, 0, stream>>>(esrc, edst, bcursor, part);
    k_csr<<<NB, 256, 0, stream>>>(part, bbase, offs, dis, csr, coef);

    // Layer 1
    k_gemm<<<(NN + 127) / 128, 256, 0, stream>>>(x, W1, dis, hs);
    k_agg1<<<NN / 4, 256, 0, stream>>>((const unsigned short*)hs, dis, offs, csr, b1, g);

    // Layer 2 (collapsed): weighted row-sum of g, then 128x128 matvec
    k_wsum<<<NWB, 256, 0, stream>>>(g, coef, dis, partials);
    k_out<<<1, 128, 0, stream>>>(partials, W2, b2, out);
}

// Round 5
// 243.491 us; speedup vs baseline: 2.4379x; 1.1933x over previous
//
#include <hip/hip_runtime.h>

#define NN 100000
#define NE 1600000
#define DD 128
#define NB 196          // ceil(NN/512) buckets of 512 nodes
#define NWB 256         // k_wsum partial blocks

typedef float f32x2 __attribute__((ext_vector_type(2)));
typedef float f32x4 __attribute__((ext_vector_type(4)));
typedef short s16x8 __attribute__((ext_vector_type(8)));

static __device__ __forceinline__ unsigned short f2bf(float f) {
    unsigned u = __float_as_uint(f);
    return (unsigned short)((u + 0x7fffu + ((u >> 16) & 1u)) >> 16);
}

// ---------------- CSR build ----------------

__global__ __launch_bounds__(256) void k_bhist(const int* __restrict__ dst, int* __restrict__ bhist) {
    __shared__ int h[NB];
    int t = threadIdx.x;
    if (t < NB) h[t] = 0;
    __syncthreads();
    for (int i = blockIdx.x * 256 + t; i < NE; i += gridDim.x * 256)
        atomicAdd(&h[dst[i] >> 9], 1);
    __syncthreads();
    if (t < NB) atomicAdd(&bhist[t], h[t]);
}

__global__ __launch_bounds__(256) void k_bscan(const int* __restrict__ bhist, int* __restrict__ bbase,
                                               int* __restrict__ bcursor, int* __restrict__ offs) {
    __shared__ int sd[256];
    int t = threadIdx.x;
    int v = (t < NB) ? bhist[t] : 0;
    sd[t] = v;
    __syncthreads();
    for (int off = 1; off < 256; off <<= 1) {
        int a = (t >= off) ? sd[t - off] : 0;
        __syncthreads();
        sd[t] += a;
        __syncthreads();
    }
    if (t < NB) { int e = sd[t] - v; bbase[t] = e; bcursor[t] = e; }
    if (t == 0) { bbase[NB] = NE; offs[NN] = NE; }
}

// partition edges into buckets; record packed as (local_dst<<17)|src
__global__ __launch_bounds__(256) void k_part(const int* __restrict__ src, const int* __restrict__ dst,
                                              int* __restrict__ bcursor, unsigned* __restrict__ part) {
    __shared__ int hist[NB], rank[NB], bbl[NB];
    int t = threadIdx.x;
    if (t < NB) hist[t] = 0;
    __syncthreads();
    int base = blockIdx.x * 4096;
    int s[16], d[16];
    #pragma unroll
    for (int j = 0; j < 16; j++) {
        int i = base + j * 256 + t;
        if (i < NE) { s[j] = src[i]; d[j] = dst[i]; atomicAdd(&hist[d[j] >> 9], 1); }
        else d[j] = -1;
    }
    __syncthreads();
    if (t < NB) { bbl[t] = atomicAdd(&bcursor[t], hist[t]); rank[t] = 0; }
    __syncthreads();
    #pragma unroll
    for (int j = 0; j < 16; j++) {
        if (d[j] >= 0) {
            int b = d[j] >> 9;
            int r = atomicAdd(&rank[b], 1);
            part[bbl[b] + r] = (unsigned)s[j] | ((unsigned)(d[j] & 511) << 17);
        }
    }
}

// per-bucket CSR + dis (round-3 form, no coef)
__global__ __launch_bounds__(256) void k_csr(const unsigned* __restrict__ part, const int* __restrict__ bbase,
                                             int* __restrict__ offs, float* __restrict__ dis,
                                             int* __restrict__ csr) {
    __shared__ int cnt[512], offl[512], s2[256];
    int t = threadIdx.x;
    int b = blockIdx.x;
    int dlo = b << 9;
    int nn_b = NN - dlo; if (nn_b > 512) nn_b = 512;
    int e0 = bbase[b], e1 = bbase[b + 1];
    cnt[t] = 0; cnt[t + 256] = 0;
    __syncthreads();
    for (int i = e0 + t; i < e1; i += 256)
        atomicAdd(&cnt[part[i] >> 17], 1);
    __syncthreads();
    int a0 = cnt[2 * t], a1 = cnt[2 * t + 1];
    s2[t] = a0 + a1;
    __syncthreads();
    for (int off = 1; off < 256; off <<= 1) {
        int a = (t >= off) ? s2[t - off] : 0;
        __syncthreads();
        s2[t] += a;
        __syncthreads();
    }
    int ex = s2[t] - (a0 + a1);
    offl[2 * t] = ex; offl[2 * t + 1] = ex + a0;
    __syncthreads();
    #pragma unroll
    for (int q = 0; q < 2; q++) {
        int i = t + q * 256;
        if (i < nn_b) {
            offs[dlo + i] = e0 + offl[i];
            dis[dlo + i] = rsqrtf((float)cnt[i] + 1.0f);
        }
    }
    __syncthreads();
    cnt[t] = 0; cnt[t + 256] = 0;
    __syncthreads();
    for (int i = e0 + t; i < e1; i += 256) {
        unsigned e = part[i];
        int li = (int)(e >> 17);
        int p = e0 + offl[li] + atomicAdd(&cnt[li], 1);
        csr[p] = (int)(e & 0x1FFFFu);
    }
}

// ---------------- MFMA GEMM: hs[r,:] = fp8( dis[r] * (x[r,:] @ W1) ) ----------------

__global__ __launch_bounds__(256) void k_gemm(const float* __restrict__ Ap, const float* __restrict__ W,
                                              const float* __restrict__ dis, unsigned* __restrict__ hs) {
    __shared__ unsigned WF[8192];   // 8nt x 4kk x 64lane x 4 u32 (bf16 pairs), 32KB
    int tid = threadIdx.x;
    #pragma unroll
    for (int i = 0; i < 32; i++) {
        int e = i * 256 + tid;
        int jw = e & 3, lane = (e >> 2) & 63, kk = (e >> 8) & 3, nt = e >> 10;
        int r0 = kk * 32 + ((lane >> 4) << 3) + (jw << 1);
        int c = (nt << 4) + (lane & 15);
        unsigned lo = f2bf(W[r0 * DD + c]);
        unsigned hi = f2bf(W[(r0 + 1) * DD + c]);
        WF[e] = lo | (hi << 16);
    }
    __syncthreads();

    int lane = tid & 63;
    int w = tid >> 6;
    int rowBase = blockIdx.x * 128 + w * 32;
    int lg = lane >> 4;
    int ll = lane & 15;

    f32x4 acc[2][8];
    #pragma unroll
    for (int m = 0; m < 2; m++)
        #pragma unroll
        for (int n = 0; n < 8; n++) acc[m][n] = (f32x4){0.f, 0.f, 0.f, 0.f};

    const s16x8* wfrag = (const s16x8*)WF;

    for (int kk = 0; kk < 4; kk++) {
        s16x8 af[2];
        #pragma unroll
        for (int mt = 0; mt < 2; mt++) {
            int r = rowBase + mt * 16 + ll;
            if (r >= NN) r = NN - 1;
            const float* xp = Ap + (size_t)r * DD + kk * 32 + lg * 8;
            f32x4 a0 = *(const f32x4*)xp;
            f32x4 a1 = *(const f32x4*)(xp + 4);
            s16x8 tt;
            tt[0] = (short)f2bf(a0[0]); tt[1] = (short)f2bf(a0[1]);
            tt[2] = (short)f2bf(a0[2]); tt[3] = (short)f2bf(a0[3]);
            tt[4] = (short)f2bf(a1[0]); tt[5] = (short)f2bf(a1[1]);
            tt[6] = (short)f2bf(a1[2]); tt[7] = (short)f2bf(a1[3]);
            af[mt] = tt;
        }
        #pragma unroll
        for (int nt = 0; nt < 8; nt++) {
            s16x8 bf = wfrag[(nt * 4 + kk) * 64 + lane];
            acc[0][nt] = __builtin_amdgcn_mfma_f32_16x16x32_bf16(bf, af[0], acc[0][nt], 0, 0, 0);
            acc[1][nt] = __builtin_amdgcn_mfma_f32_16x16x32_bf16(bf, af[1], acc[1][nt], 0, 0, 0);
        }
    }

    #pragma unroll
    for (int mt = 0; mt < 2; mt++) {
        int grow = rowBase + mt * 16 + ll;
        if (grow < NN) {
            float dn = dis[grow];
            unsigned* orow = hs + (size_t)grow * 32;
            #pragma unroll
            for (int nt = 0; nt < 8; nt++) {
                f32x4 v = acc[mt][nt];
                int u = 0;
                u = __builtin_amdgcn_cvt_pk_fp8_f32(v[0] * dn, v[1] * dn, u, false);
                u = __builtin_amdgcn_cvt_pk_fp8_f32(v[2] * dn, v[3] * dn, u, true);
                orow[nt * 4 + lg] = (unsigned)u;
            }
        }
    }
}

// ---------------- Aggregation layer 1 (half-wave rows, 8 edges/iter) + coef scatter ----------------
// Each half-wave (32 lanes x u32) reads a full 128B fp8 row; per-lane 4-col f32 accs;
// halves combined via shfl_xor(32). OOB edges read zeroed dummy row NN.
// coef[s] += dis[node] fired by lane 0 of each half (fire-and-forget atomics).

__global__ __launch_bounds__(256) void k_agg1(const unsigned* __restrict__ hs4, const float* __restrict__ dis,
                                              const int* __restrict__ offs, const int* __restrict__ csr,
                                              const float* __restrict__ bias, unsigned* __restrict__ g,
                                              float* __restrict__ coef) {
    int lane = threadIdx.x & 63;
    int half = lane >> 5;
    int li = lane & 31;
    int node = blockIdx.x * 4 + (threadIdx.x >> 6);
    int beg = offs[node], end = offs[node + 1];
    float dn = dis[node];
    float a0 = 0.f, a1 = 0.f, a2 = 0.f, a3 = 0.f;

    for (int i = beg; i < end; i += 8) {
        int idx = i + half * 4;
        int s0 = (idx + 0 < end) ? csr[idx + 0] : NN;
        int s1 = (idx + 1 < end) ? csr[idx + 1] : NN;
        int s2 = (idx + 2 < end) ? csr[idx + 2] : NN;
        int s3 = (idx + 3 < end) ? csr[idx + 3] : NN;
        unsigned r0 = hs4[s0 * 32 + li];
        unsigned r1 = hs4[s1 * 32 + li];
        unsigned r2 = hs4[s2 * 32 + li];
        unsigned r3 = hs4[s3 * 32 + li];
        if (li == 0) {
            if (s0 != NN) atomicAdd(&coef[s0], dn);
            if (s1 != NN) atomicAdd(&coef[s1], dn);
            if (s2 != NN) atomicAdd(&coef[s2], dn);
            if (s3 != NN) atomicAdd(&coef[s3], dn);
        }
        f32x2 p0 = __builtin_amdgcn_cvt_pk_f32_fp8(r0, false), q0 = __builtin_amdgcn_cvt_pk_f32_fp8(r0, true);
        f32x2 p1 = __builtin_amdgcn_cvt_pk_f32_fp8(r1, false), q1 = __builtin_amdgcn_cvt_pk_f32_fp8(r1, true);
        f32x2 p2 = __builtin_amdgcn_cvt_pk_f32_fp8(r2, false), q2 = __builtin_amdgcn_cvt_pk_f32_fp8(r2, true);
        f32x2 p3 = __builtin_amdgcn_cvt_pk_f32_fp8(r3, false), q3 = __builtin_amdgcn_cvt_pk_f32_fp8(r3, true);
        a0 += p0[0] + p1[0] + p2[0] + p3[0];
        a1 += p0[1] + p1[1] + p2[1] + p3[1];
        a2 += q0[0] + q1[0] + q2[0] + q3[0];
        a3 += q0[1] + q1[1] + q2[1] + q3[1];
    }

    a0 += __shfl_xor(a0, 32);
    a1 += __shfl_xor(a1, 32);
    a2 += __shfl_xor(a2, 32);
    a3 += __shfl_xor(a3, 32);

    if (half == 0) {
        unsigned su = hs4[node * 32 + li];
        f32x2 sl = __builtin_amdgcn_cvt_pk_f32_fp8(su, false);
        f32x2 sh = __builtin_amdgcn_cvt_pk_f32_fp8(su, true);
        f32x4 bv = *(const f32x4*)&bias[li * 4];
        float o0 = fmaxf(dn * (a0 + sl[0]) + bv[0], 0.f);
        float o1 = fmaxf(dn * (a1 + sl[1]) + bv[1], 0.f);
        float o2 = fmaxf(dn * (a2 + sh[0]) + bv[2], 0.f);
        float o3 = fmaxf(dn * (a3 + sh[1]) + bv[3], 0.f);
        unsigned w0 = (unsigned)f2bf(o0) | ((unsigned)f2bf(o1) << 16);
        unsigned w1 = (unsigned)f2bf(o2) | ((unsigned)f2bf(o3) << 16);
        uint2 pk = {w0, w1};
        *(uint2*)&g[node * 64 + li * 2] = pk;
    }
}

// ---------------- Layer 2 collapsed: v = sum_s (coef[s]+dis[s])*dis[s] * g[s] ----------------

__global__ __launch_bounds__(256) void k_wsum(const unsigned* __restrict__ g, const float* __restrict__ coef,
                                              const float* __restrict__ dis, float* __restrict__ partials) {
    __shared__ float red[4][DD];
    int lane = threadIdx.x & 63;
    int w = threadIdx.x >> 6;
    int wid = blockIdx.x * 4 + w;          // 0..1023
    float ax = 0.f, ay = 0.f;
    for (int n0 = wid; n0 < NN; n0 += 4096) {
        #pragma unroll
        for (int q = 0; q < 4; q++) {
            int node = n0 + q * 1024;
            if (node < NN) {
                float dn = dis[node];
                float wt = (coef[node] + dn) * dn;
                unsigned u = g[node * 64 + lane];
                ax += wt * __uint_as_float(u << 16);
                ay += wt * __uint_as_float(u & 0xffff0000u);
            }
        }
    }
    red[w][2 * lane] = ax; red[w][2 * lane + 1] = ay;
    __syncthreads();
    if (w == 0) {
        float sx = red[0][2 * lane] + red[1][2 * lane] + red[2][2 * lane] + red[3][2 * lane];
        float sy = red[0][2 * lane + 1] + red[1][2 * lane + 1] + red[2][2 * lane + 1] + red[3][2 * lane + 1];
        partials[blockIdx.x * DD + 2 * lane] = sx;
        partials[blockIdx.x * DD + 2 * lane + 1] = sy;
    }
}

// out[t] = (1/N) * sum_k v[k] * W2[k][t] + b2[t]
__global__ __launch_bounds__(128) void k_out(const float* __restrict__ partials, const float* __restrict__ W2,
                                             const float* __restrict__ b2, float* __restrict__ out) {
    __shared__ float v[DD];
    int t = threadIdx.x;
    float s = 0.f;
    for (int p = 0; p < NWB; p++) s += partials[p * DD + t];
    v[t] = s * (1.0f / NN);
    __syncthreads();
    float o = b2[t];
    for (int k = 0; k < DD; k++) o += v[k] * W2[k * DD + t];
    out[t] = o;
}

// ---------------- launch ----------------

extern "C" void kernel_launch(void* const* d_in, const int* in_sizes, int n_in,
                              void* d_out, int out_size, void* d_ws, size_t ws_size,
                              hipStream_t stream) {
    const float* x  = (const float*)d_in[0];
    const int*   ei = (const int*)d_in[1];
    const float* W1 = (const float*)d_in[2];
    const float* b1 = (const float*)d_in[3];
    const float* W2 = (const float*)d_in[4];
    const float* b2 = (const float*)d_in[5];
    float* out = (float*)d_out;
    const int* esrc = ei;
    const int* edst = ei + NE;

    char* p = (char*)d_ws;
    unsigned* part = (unsigned*)p;       p += (size_t)NE * 4;
    int* csr       = (int*)p;            p += (size_t)NE * 4;
    int* offs      = (int*)p;            p += (((size_t)(NN + 1) * 4) + 255) & ~(size_t)255;
    float* dis     = (float*)p;          p += (((size_t)NN * 4) + 255) & ~(size_t)255;
    float* coef    = (float*)p;          p += (((size_t)NN * 4) + 255) & ~(size_t)255;
    int* bhist     = (int*)p;            p += 1024;
    int* bbase     = (int*)p;            p += 1024;
    int* bcursor   = (int*)p;            p += 1024;
    unsigned* hs   = (unsigned*)p;       p += (size_t)(NN + 1) * DD;    // fp8 rows + zero dummy row
    unsigned* g    = (unsigned*)p;       p += (size_t)NN * DD * 2;      // bf16
    float* partials = (float*)p;         p += (size_t)NWB * DD * 4;

    // CSR build
    hipMemsetAsync(bhist, 0, NB * 4, stream);
    hipMemsetAsync(coef, 0, NN * 4, stream);
    hipMemsetAsync(hs + (size_t)NN * 32, 0, DD, stream);   // zero dummy row
    k_bhist<<<256, 256, 0, stream>>>(edst, bhist);
    k_bscan<<<1, 256, 0, stream>>>(bhist, bbase, bcursor, offs);
    k_part<<<(NE + 4095) / 4096, 256, 0, stream>>>(esrc, edst, bcursor, part);
    k_csr<<<NB, 256, 0, stream>>>(part, bbase, offs, dis, csr);

    // Layer 1
    k_gemm<<<(NN + 127) / 128, 256, 0, stream>>>(x, W1, dis, hs);
    k_agg1<<<NN / 4, 256, 0, stream>>>(hs, dis, offs, csr, b1, g, coef);

    // Layer 2 (collapsed): weighted row-sum of g, then 128x128 matvec
    k_wsum<<<NWB, 256, 0, stream>>>(g, coef, dis, partials);
    k_out<<<1, 128, 0, stream>>>(partials, W2, b2, out);
}

// Round 6
// 238.398 us; speedup vs baseline: 2.4900x; 1.0214x over previous
//
#include <hip/hip_runtime.h>

#define NN 100000
#define NE 1600000
#define DD 128
#define NB 782          // ceil(NN/128) buckets of 128 nodes
#define BSH 7           // bucket shift
#define NWB 256         // k_wsum partial blocks

typedef float f32x2 __attribute__((ext_vector_type(2)));
typedef float f32x4 __attribute__((ext_vector_type(4)));
typedef short s16x8 __attribute__((ext_vector_type(8)));

static __device__ __forceinline__ unsigned short f2bf(float f) {
    unsigned u = __float_as_uint(f);
    return (unsigned short)((u + 0x7fffu + ((u >> 16) & 1u)) >> 16);
}

// ---------------- CSR build ----------------

__global__ __launch_bounds__(256) void k_bhist(const int* __restrict__ dst, int* __restrict__ bhist) {
    __shared__ int h[NB];
    int t = threadIdx.x;
    for (int j = t; j < NB; j += 256) h[j] = 0;
    __syncthreads();
    for (int i = blockIdx.x * 256 + t; i < NE; i += gridDim.x * 256)
        atomicAdd(&h[dst[i] >> BSH], 1);
    __syncthreads();
    for (int j = t; j < NB; j += 256) atomicAdd(&bhist[j], h[j]);
}

__global__ __launch_bounds__(256) void k_bscan(const int* __restrict__ bhist, int* __restrict__ bbase,
                                               int* __restrict__ bcursor, int* __restrict__ offs) {
    __shared__ int sd[256];
    int t = threadIdx.x;
    int base = t * 4;
    int v0 = (base + 0 < NB) ? bhist[base + 0] : 0;
    int v1 = (base + 1 < NB) ? bhist[base + 1] : 0;
    int v2 = (base + 2 < NB) ? bhist[base + 2] : 0;
    int v3 = (base + 3 < NB) ? bhist[base + 3] : 0;
    int s = v0 + v1 + v2 + v3;
    sd[t] = s;
    __syncthreads();
    for (int off = 1; off < 256; off <<= 1) {
        int a = (t >= off) ? sd[t - off] : 0;
        __syncthreads();
        sd[t] += a;
        __syncthreads();
    }
    int run = sd[t] - s;
    if (base + 0 < NB) { bbase[base + 0] = run; bcursor[base + 0] = run; } run += v0;
    if (base + 1 < NB) { bbase[base + 1] = run; bcursor[base + 1] = run; } run += v1;
    if (base + 2 < NB) { bbase[base + 2] = run; bcursor[base + 2] = run; } run += v2;
    if (base + 3 < NB) { bbase[base + 3] = run; bcursor[base + 3] = run; }
    if (t == 0) { bbase[NB] = NE; offs[NN] = NE; }
}

// partition edges into buckets; record packed as (local_dst<<17)|src  (local 7b, src 17b)
__global__ __launch_bounds__(256) void k_part(const int* __restrict__ src, const int* __restrict__ dst,
                                              int* __restrict__ bcursor, unsigned* __restrict__ part) {
    __shared__ int hist[NB], rank[NB], bbl[NB];
    int t = threadIdx.x;
    for (int j = t; j < NB; j += 256) hist[j] = 0;
    __syncthreads();
    int base = blockIdx.x * 4096;
    int s[16], d[16];
    #pragma unroll
    for (int j = 0; j < 16; j++) {
        int i = base + j * 256 + t;
        if (i < NE) { s[j] = src[i]; d[j] = dst[i]; atomicAdd(&hist[d[j] >> BSH], 1); }
        else d[j] = -1;
    }
    __syncthreads();
    for (int j = t; j < NB; j += 256) { bbl[j] = atomicAdd(&bcursor[j], hist[j]); rank[j] = 0; }
    __syncthreads();
    #pragma unroll
    for (int j = 0; j < 16; j++) {
        if (d[j] >= 0) {
            int b = d[j] >> BSH;
            int r = atomicAdd(&rank[b], 1);
            part[bbl[b] + r] = (unsigned)s[j] | ((unsigned)(d[j] & 127) << 17);
        }
    }
}

// per-bucket (128 nodes) CSR + dis
__global__ __launch_bounds__(256) void k_csr(const unsigned* __restrict__ part, const int* __restrict__ bbase,
                                             int* __restrict__ offs, float* __restrict__ dis,
                                             int* __restrict__ csr) {
    __shared__ int cnt[128], offl[128], s2[128];
    int t = threadIdx.x;
    int b = blockIdx.x;
    int dlo = b << BSH;
    int nn_b = NN - dlo; if (nn_b > 128) nn_b = 128;
    int e0 = bbase[b], e1 = bbase[b + 1];
    if (t < 128) cnt[t] = 0;
    __syncthreads();
    for (int i = e0 + t; i < e1; i += 256)
        atomicAdd(&cnt[part[i] >> 17], 1);
    __syncthreads();
    int a = (t < 128) ? cnt[t] : 0;
    if (t < 128) s2[t] = a;
    __syncthreads();
    for (int off = 1; off < 128; off <<= 1) {
        int add = (t < 128 && t >= off) ? s2[t - off] : 0;
        __syncthreads();
        if (t < 128) s2[t] += add;
        __syncthreads();
    }
    if (t < 128) {
        int ex = s2[t] - a;
        offl[t] = ex;
        if (t < nn_b) {
            offs[dlo + t] = e0 + ex;
            dis[dlo + t] = rsqrtf((float)a + 1.0f);
        }
        cnt[t] = 0;
    }
    __syncthreads();
    for (int i = e0 + t; i < e1; i += 256) {
        unsigned e = part[i];
        int li = (int)(e >> 17);
        int p = e0 + offl[li] + atomicAdd(&cnt[li], 1);
        csr[p] = (int)(e & 0x1FFFFu);
    }
}

// ---------------- MFMA GEMM: hs[r,:] = fp8( dis[r] * (x[r,:] @ W1) ) ----------------

__global__ __launch_bounds__(256) void k_gemm(const float* __restrict__ Ap, const float* __restrict__ W,
                                              const float* __restrict__ dis, unsigned* __restrict__ hs) {
    __shared__ unsigned WF[8192];   // 8nt x 4kk x 64lane x 4 u32 (bf16 pairs), 32KB
    int tid = threadIdx.x;
    #pragma unroll
    for (int i = 0; i < 32; i++) {
        int e = i * 256 + tid;
        int jw = e & 3, lane = (e >> 2) & 63, kk = (e >> 8) & 3, nt = e >> 10;
        int r0 = kk * 32 + ((lane >> 4) << 3) + (jw << 1);
        int c = (nt << 4) + (lane & 15);
        unsigned lo = f2bf(W[r0 * DD + c]);
        unsigned hi = f2bf(W[(r0 + 1) * DD + c]);
        WF[e] = lo | (hi << 16);
    }
    __syncthreads();

    int lane = tid & 63;
    int w = tid >> 6;
    int rowBase = blockIdx.x * 128 + w * 32;
    int lg = lane >> 4;
    int ll = lane & 15;

    f32x4 acc[2][8];
    #pragma unroll
    for (int m = 0; m < 2; m++)
        #pragma unroll
        for (int n = 0; n < 8; n++) acc[m][n] = (f32x4){0.f, 0.f, 0.f, 0.f};

    const s16x8* wfrag = (const s16x8*)WF;

    for (int kk = 0; kk < 4; kk++) {
        s16x8 af[2];
        #pragma unroll
        for (int mt = 0; mt < 2; mt++) {
            int r = rowBase + mt * 16 + ll;
            if (r >= NN) r = NN - 1;
            const float* xp = Ap + (size_t)r * DD + kk * 32 + lg * 8;
            f32x4 a0 = *(const f32x4*)xp;
            f32x4 a1 = *(const f32x4*)(xp + 4);
            s16x8 tt;
            tt[0] = (short)f2bf(a0[0]); tt[1] = (short)f2bf(a0[1]);
            tt[2] = (short)f2bf(a0[2]); tt[3] = (short)f2bf(a0[3]);
            tt[4] = (short)f2bf(a1[0]); tt[5] = (short)f2bf(a1[1]);
            tt[6] = (short)f2bf(a1[2]); tt[7] = (short)f2bf(a1[3]);
            af[mt] = tt;
        }
        #pragma unroll
        for (int nt = 0; nt < 8; nt++) {
            s16x8 bf = wfrag[(nt * 4 + kk) * 64 + lane];
            acc[0][nt] = __builtin_amdgcn_mfma_f32_16x16x32_bf16(bf, af[0], acc[0][nt], 0, 0, 0);
            acc[1][nt] = __builtin_amdgcn_mfma_f32_16x16x32_bf16(bf, af[1], acc[1][nt], 0, 0, 0);
        }
    }

    #pragma unroll
    for (int mt = 0; mt < 2; mt++) {
        int grow = rowBase + mt * 16 + ll;
        if (grow < NN) {
            float dn = dis[grow];
            unsigned* orow = hs + (size_t)grow * 32;
            #pragma unroll
            for (int nt = 0; nt < 8; nt++) {
                f32x4 v = acc[mt][nt];
                int u = 0;
                u = __builtin_amdgcn_cvt_pk_fp8_f32(v[0] * dn, v[1] * dn, u, false);
                u = __builtin_amdgcn_cvt_pk_fp8_f32(v[2] * dn, v[3] * dn, u, true);
                orow[nt * 4 + lg] = (unsigned)u;
            }
        }
    }
}

// ---------------- Aggregation layer 1: 16 edges/iter (8 rows per half-wave) + coef scatter ----------------

__global__ __launch_bounds__(256) void k_agg1(const unsigned* __restrict__ hs4, const float* __restrict__ dis,
                                              const int* __restrict__ offs, const int* __restrict__ csr,
                                              const float* __restrict__ bias, unsigned* __restrict__ g,
                                              float* __restrict__ coef) {
    int lane = threadIdx.x & 63;
    int half = lane >> 5;
    int li = lane & 31;
    int node = blockIdx.x * 4 + (threadIdx.x >> 6);
    int beg = offs[node], end = offs[node + 1];
    float dn = dis[node];
    float a0 = 0.f, a1 = 0.f, a2 = 0.f, a3 = 0.f;

    for (int i = beg; i < end; i += 16) {
        int idx = i + half * 8;
        int s[8];
        unsigned r[8];
        #pragma unroll
        for (int j = 0; j < 8; j++) s[j] = (idx + j < end) ? csr[idx + j] : NN;
        #pragma unroll
        for (int j = 0; j < 8; j++) r[j] = hs4[s[j] * 32 + li];
        if (li == 0) {
            #pragma unroll
            for (int j = 0; j < 8; j++) if (s[j] != NN) atomicAdd(&coef[s[j]], dn);
        }
        #pragma unroll
        for (int j = 0; j < 8; j++) {
            f32x2 pl = __builtin_amdgcn_cvt_pk_f32_fp8(r[j], false);
            f32x2 ph = __builtin_amdgcn_cvt_pk_f32_fp8(r[j], true);
            a0 += pl[0]; a1 += pl[1]; a2 += ph[0]; a3 += ph[1];
        }
    }

    a0 += __shfl_xor(a0, 32);
    a1 += __shfl_xor(a1, 32);
    a2 += __shfl_xor(a2, 32);
    a3 += __shfl_xor(a3, 32);

    if (half == 0) {
        unsigned su = hs4[node * 32 + li];
        f32x2 sl = __builtin_amdgcn_cvt_pk_f32_fp8(su, false);
        f32x2 sh = __builtin_amdgcn_cvt_pk_f32_fp8(su, true);
        f32x4 bv = *(const f32x4*)&bias[li * 4];
        float o0 = fmaxf(dn * (a0 + sl[0]) + bv[0], 0.f);
        float o1 = fmaxf(dn * (a1 + sl[1]) + bv[1], 0.f);
        float o2 = fmaxf(dn * (a2 + sh[0]) + bv[2], 0.f);
        float o3 = fmaxf(dn * (a3 + sh[1]) + bv[3], 0.f);
        unsigned w0 = (unsigned)f2bf(o0) | ((unsigned)f2bf(o1) << 16);
        unsigned w1 = (unsigned)f2bf(o2) | ((unsigned)f2bf(o3) << 16);
        uint2 pk = {w0, w1};
        *(uint2*)&g[node * 64 + li * 2] = pk;
    }
}

// ---------------- Layer 2 collapsed: v = sum_s (coef[s]+dis[s])*dis[s] * g[s] ----------------

__global__ __launch_bounds__(256) void k_wsum(const unsigned* __restrict__ g, const float* __restrict__ coef,
                                              const float* __restrict__ dis, float* __restrict__ partials) {
    __shared__ float red[4][DD];
    int lane = threadIdx.x & 63;
    int w = threadIdx.x >> 6;
    int wid = blockIdx.x * 4 + w;          // 0..1023
    float ax = 0.f, ay = 0.f;
    for (int n0 = wid; n0 < NN; n0 += 4096) {
        #pragma unroll
        for (int q = 0; q < 4; q++) {
            int node = n0 + q * 1024;
            if (node < NN) {
                float dn = dis[node];
                float wt = (coef[node] + dn) * dn;
                unsigned u = g[node * 64 + lane];
                ax += wt * __uint_as_float(u << 16);
                ay += wt * __uint_as_float(u & 0xffff0000u);
            }
        }
    }
    red[w][2 * lane] = ax; red[w][2 * lane + 1] = ay;
    __syncthreads();
    if (w == 0) {
        float sx = red[0][2 * lane] + red[1][2 * lane] + red[2][2 * lane] + red[3][2 * lane];
        float sy = red[0][2 * lane + 1] + red[1][2 * lane + 1] + red[2][2 * lane + 1] + red[3][2 * lane + 1];
        partials[blockIdx.x * DD + 2 * lane] = sx;
        partials[blockIdx.x * DD + 2 * lane + 1] = sy;
    }
}

// out[t] = (1/N) * sum_k v[k] * W2[k][t] + b2[t]
__global__ __launch_bounds__(128) void k_out(const float* __restrict__ partials, const float* __restrict__ W2,
                                             const float* __restrict__ b2, float* __restrict__ out) {
    __shared__ float v[DD];
    int t = threadIdx.x;
    float s = 0.f;
    for (int p = 0; p < NWB; p++) s += partials[p * DD + t];
    v[t] = s * (1.0f / NN);
    __syncthreads();
    float o = b2[t];
    for (int k = 0; k < DD; k++) o += v[k] * W2[k * DD + t];
    out[t] = o;
}

// ---------------- launch ----------------

extern "C" void kernel_launch(void* const* d_in, const int* in_sizes, int n_in,
                              void* d_out, int out_size, void* d_ws, size_t ws_size,
                              hipStream_t stream) {
    const float* x  = (const float*)d_in[0];
    const int*   ei = (const int*)d_in[1];
    const float* W1 = (const float*)d_in[2];
    const float* b1 = (const float*)d_in[3];
    const float* W2 = (const float*)d_in[4];
    const float* b2 = (const float*)d_in[5];
    float* out = (float*)d_out;
    const int* esrc = ei;
    const int* edst = ei + NE;

    char* p = (char*)d_ws;
    unsigned* part = (unsigned*)p;       p += (size_t)NE * 4;
    int* csr       = (int*)p;            p += (size_t)NE * 4;
    int* offs      = (int*)p;            p += (((size_t)(NN + 1) * 4) + 255) & ~(size_t)255;
    float* dis     = (float*)p;          p += (((size_t)NN * 4) + 255) & ~(size_t)255;
    float* coef    = (float*)p;          p += (((size_t)NN * 4) + 255) & ~(size_t)255;
    int* bhist     = (int*)p;            p += (((size_t)NB * 4) + 255) & ~(size_t)255;
    int* bbase     = (int*)p;            p += (((size_t)(NB + 1) * 4) + 255) & ~(size_t)255;
    int* bcursor   = (int*)p;            p += (((size_t)NB * 4) + 255) & ~(size_t)255;
    unsigned* hs   = (unsigned*)p;       p += (size_t)(NN + 1) * DD;    // fp8 rows + zero dummy row
    unsigned* g    = (unsigned*)p;       p += (size_t)NN * DD * 2;      // bf16
    float* partials = (float*)p;         p += (size_t)NWB * DD * 4;

    // CSR build
    hipMemsetAsync(bhist, 0, NB * 4, stream);
    hipMemsetAsync(coef, 0, NN * 4, stream);
    hipMemsetAsync(hs + (size_t)NN * 32, 0, DD, stream);   // zero dummy row
    k_bhist<<<256, 256, 0, stream>>>(edst, bhist);
    k_bscan<<<1, 256, 0, stream>>>(bhist, bbase, bcursor, offs);
    k_part<<<(NE + 4095) / 4096, 256, 0, stream>>>(esrc, edst, bcursor, part);
    k_csr<<<NB, 256, 0, stream>>>(part, bbase, offs, dis, csr);

    // Layer 1
    k_gemm<<<(NN + 127) / 128, 256, 0, stream>>>(x, W1, dis, hs);
    k_agg1<<<NN / 4, 256, 0, stream>>>(hs, dis, offs, csr, b1, g, coef);

    // Layer 2 (collapsed): weighted row-sum of g, then 128x128 matvec
    k_wsum<<<NWB, 256, 0, stream>>>(g, coef, dis, partials);
    k_out<<<1, 128, 0, stream>>>(partials, W2, b2, out);
}